// Round 12
// baseline (267.597 us; speedup 1.0000x reference)
//
#include <hip/hip_runtime.h>
#include <hip/hip_fp16.h>

typedef _Float16 half8 __attribute__((ext_vector_type(8)));
typedef _Float16 half4 __attribute__((ext_vector_type(4)));
typedef __fp16  fp16x2 __attribute__((ext_vector_type(2)));
typedef float f32x4 __attribute__((ext_vector_type(4)));

#define BB 4
#define NB 8
#define LL 512
#define SS 512
#define HH 8
#define EE 64
#define ROWSTRIDE (HH * EE)   // 512 floats between consecutive l (or s) rows

__device__ __forceinline__ unsigned pkh(float a, float b) {
    union { fp16x2 h; unsigned u; } c;
    c.h = __builtin_amdgcn_cvt_pkrtz(a, b);
    return c.u;
}

// R4 compute body, SINGLE-buffered K/V LDS (48 KiB total -> 3 blocks/CU =
// 6 waves/SIMD, +50% TLP vs R4's 2 blocks). T14 reg staging already hides
// global latency, so double-buffering only paid LDS; Pbuf is wave-private
// (no barrier needed). Schedule/tile: load(t+1) -> compute(t) -> barrier ->
// write(t+1) -> barrier. S-tile stays 64 (R5 lesson: don't shrink tiles).
// R7/R9 lesson: no extra live tile state; VGPR must stay <= ~85 for 6 w/SIMD.

__global__ __launch_bounds__(512, 6) void cattn_kernel(
    const float* __restrict__ qre, const float* __restrict__ qim,
    const float* __restrict__ kre, const float* __restrict__ kim,
    const float* __restrict__ vre, const float* __restrict__ vim,
    float* __restrict__ out)
{
    // 48 KiB total LDS -> 3 blocks/CU
    __shared__ __align__(16) _Float16 KtRe[64 * 64];   // [s][e] swizzled
    __shared__ __align__(16) _Float16 KtIm[64 * 64];
    __shared__ __align__(16) _Float16 VtRe[64 * 64];   // [d][s] swizzled
    __shared__ __align__(16) _Float16 VtIm[64 * 64];
    __shared__ __align__(16) _Float16 Pbuf[8][16 * 64]; // per-wave P[l][s] swizzled

    const int tid  = threadIdx.x;
    const int wave = tid >> 6;
    const int lane = tid & 63;
    const int lgrp = lane >> 4;   // 0..3
    const int l16  = lane & 15;   // 0..15

    // bijective XCD swizzle: nwg=1024, 8 XCDs, 128 blocks per XCD chunk
    const int bid  = blockIdx.x;
    const int nid  = (bid & 7) * 128 + (bid >> 3);
    const int lt   = nid & 3;     // L-tile (128 rows)
    const int head = nid >> 2;    // 0..255
    const int h    = head & 7;
    const int bn   = head >> 3;

    const size_t headQ = (size_t)bn * LL * ROWSTRIDE + (size_t)h * EE;
    const size_t headK = (size_t)bn * SS * ROWSTRIDE + (size_t)h * EE;

    // staging registers (T14: load-early / write-late)
    float4 ka[2], kb[2];   // K: re/im x 8 f32
    float4 vv[4];          // V: 4 s-rows x 4 d-cols

    const int kEc0  = tid & 7;               // e-chunk
    const int kS0   = (tid >> 3) & 63;       // s-row
    const int vArr  = tid >> 8;
    const int vD0   = (tid & 15) * 4;
    const int vS0   = ((tid >> 4) & 15) * 4;

    auto stage_load = [&](int st) {
        const int tb = st * 64;
        {
            const float* p = kre + headK + (size_t)(tb + kS0) * ROWSTRIDE + kEc0 * 8;
            ka[0] = *(const float4*)p;
            kb[0] = *(const float4*)(p + 4);
        }
        {
            const float* p = kim + headK + (size_t)(tb + kS0) * ROWSTRIDE + kEc0 * 8;
            ka[1] = *(const float4*)p;
            kb[1] = *(const float4*)(p + 4);
        }
        {
            const float* src = vArr ? vim : vre;
            #pragma unroll
            for (int i = 0; i < 4; ++i)
                vv[i] = *(const float4*)(src + headK + (size_t)(tb + vS0 + i) * ROWSTRIDE + vD0);
        }
    };

    auto stage_write = [&]() {
        #pragma unroll
        for (int it = 0; it < 2; ++it) {
            union { half8 h; unsigned u[4]; } kv;
            kv.u[0] = pkh(ka[it].x, ka[it].y);
            kv.u[1] = pkh(ka[it].z, ka[it].w);
            kv.u[2] = pkh(kb[it].x, kb[it].y);
            kv.u[3] = pkh(kb[it].z, kb[it].w);
            _Float16* base = it ? KtIm : KtRe;
            *reinterpret_cast<half8*>(reinterpret_cast<char*>(base) +
                kS0 * 128 + ((kEc0 * 16) ^ ((kS0 & 7) << 4))) = kv.h;
        }
        {
            _Float16* base = vArr ? VtIm : VtRe;
            #pragma unroll
            for (int dd = 0; dd < 4; ++dd) {
                int d = vD0 + dd;
                union { half4 h; unsigned u[2]; } hv;
                hv.u[0] = pkh((&vv[0].x)[dd], (&vv[1].x)[dd]);
                hv.u[1] = pkh((&vv[2].x)[dd], (&vv[3].x)[dd]);
                *reinterpret_cast<half4*>(reinterpret_cast<char*>(base) +
                    d * 128 + ((vS0 * 2) ^ ((d & 7) << 4))) = hv.h;
            }
        }
    };

    // ---------------- Q fragments (B-operand: lane holds Q[l=l16][e=lgrp*8+j]) --
    const int l0 = lt * 128 + wave * 16;
    half8 qr[2], qin[2];   // qr and -qi
    {
        size_t base = headQ + (size_t)(l0 + l16) * ROWSTRIDE + lgrp * 8;
        #pragma unroll
        for (int ec = 0; ec < 2; ++ec) {
            float4 a0 = *(const float4*)(qre + base + ec * 32);
            float4 a1 = *(const float4*)(qre + base + ec * 32 + 4);
            float4 b0 = *(const float4*)(qim + base + ec * 32);
            float4 b1 = *(const float4*)(qim + base + ec * 32 + 4);
            #pragma unroll
            for (int j = 0; j < 4; ++j) {
                qr[ec][j]      = (_Float16)((&a0.x)[j]);
                qr[ec][4 + j]  = (_Float16)((&a1.x)[j]);
                qin[ec][j]     = (_Float16)(-(&b0.x)[j]);
                qin[ec][4 + j] = (_Float16)(-(&b1.x)[j]);
            }
        }
    }

    f32x4 ore[4], oim[4];
    #pragma unroll
    for (int n = 0; n < 4; ++n) { ore[n] = (f32x4){0.f,0.f,0.f,0.f}; oim[n] = (f32x4){0.f,0.f,0.f,0.f}; }
    float m = -1e30f, lsum = 0.f;

    stage_load(0);
    stage_write();
    __syncthreads();

    char* Pw = reinterpret_cast<char*>(&Pbuf[wave][0]);
    const int prow = l16 * 128;
    const int pswz = (l16 & 7) << 4;

    // ---------------- main loop over 8 S-tiles ----------------
    for (int st = 0; st < 8; ++st) {
        if (st < 7) stage_load(st + 1);   // loads in flight during compute

        const char* KR = (const char*)KtRe;
        const char* KI = (const char*)KtIm;
        const char* VR = (const char*)VtRe;
        const char* VI = (const char*)VtIm;

        // scores^T: lane holds mag[s = n*16 + lgrp*4 + r][l = l16]
        float p_[4][4];
        float tmax = 0.f;
        #pragma unroll
        for (int n = 0; n < 4; ++n) {
            int srow = n * 16 + l16;
            int rb   = srow * 128;
            int swz  = (srow & 7) << 4;
            half8 kr0 = *(const half8*)(KR + rb + ((lgrp * 16)      ^ swz));
            half8 kr1 = *(const half8*)(KR + rb + ((64 + lgrp * 16) ^ swz));
            half8 ki0 = *(const half8*)(KI + rb + ((lgrp * 16)      ^ swz));
            half8 ki1 = *(const half8*)(KI + rb + ((64 + lgrp * 16) ^ swz));
            f32x4 z = (f32x4){0.f,0.f,0.f,0.f};
            z = __builtin_amdgcn_mfma_f32_16x16x32_f16(kr0, qr[0],  z, 0, 0, 0);
            z = __builtin_amdgcn_mfma_f32_16x16x32_f16(kr1, qr[1],  z, 0, 0, 0);
            z = __builtin_amdgcn_mfma_f32_16x16x32_f16(ki0, qin[0], z, 0, 0, 0);
            z = __builtin_amdgcn_mfma_f32_16x16x32_f16(ki1, qin[1], z, 0, 0, 0);
            f32x4 w = (f32x4){0.f,0.f,0.f,0.f};
            w = __builtin_amdgcn_mfma_f32_16x16x32_f16(ki0, qr[0],  w, 0, 0, 0);
            w = __builtin_amdgcn_mfma_f32_16x16x32_f16(ki1, qr[1],  w, 0, 0, 0);
            w = __builtin_amdgcn_mfma_f32_16x16x32_f16(kr0, qin[0], w, 0, 0, 0);
            w = __builtin_amdgcn_mfma_f32_16x16x32_f16(kr1, qin[1], w, 0, 0, 0);
            #pragma unroll
            for (int r = 0; r < 4; ++r) {
                float mg = __builtin_amdgcn_sqrtf(z[r] * z[r] + w[r] * w[r]);
                p_[n][r] = mg;
                tmax = fmaxf(tmax, mg);
            }
        }

        // online softmax, one row per lane (4-way replicated across lgrps)
        tmax = fmaxf(tmax, __shfl_xor(tmax, 16));
        tmax = fmaxf(tmax, __shfl_xor(tmax, 32));
        float mn = fmaxf(m, tmax);
        // exact defer: if no row's max grew, sc == exp(0) == 1 -> skip rescale
        if (__any(tmax > m)) {
            float sc = __expf(m - mn);
            lsum *= sc;
            float scr[4];
            #pragma unroll
            for (int r = 0; r < 4; ++r) scr[r] = __shfl(sc, lgrp * 4 + r);
            #pragma unroll
            for (int n = 0; n < 4; ++n)
                #pragma unroll
                for (int r = 0; r < 4; ++r) { ore[n][r] *= scr[r]; oim[n][r] *= scr[r]; }
        }
        m = mn;
        float ps = 0.f;
        #pragma unroll
        for (int n = 0; n < 4; ++n)
            #pragma unroll
            for (int r = 0; r < 4; ++r) {
                float pe = __expf(p_[n][r] - mn);
                p_[n][r] = pe;
                ps += pe;
            }
        ps += __shfl_xor(ps, 16);
        ps += __shfl_xor(ps, 32);
        lsum += ps;

        // write P rows to per-wave LDS (wave-private: no barrier needed)
        #pragma unroll
        for (int n = 0; n < 4; ++n) {
            uint2 val;
            val.x = pkh(p_[n][0], p_[n][1]);
            val.y = pkh(p_[n][2], p_[n][3]);
            *reinterpret_cast<uint2*>(Pw + prow + ((n * 32 + lgrp * 8) ^ pswz)) = val;
        }

        // PV: read A-frag P[l16][kc*32+lgrp*8 ..+7] from LDS, mfma against V^T
        #pragma unroll
        for (int kc = 0; kc < 2; ++kc) {
            half8 pa = *reinterpret_cast<const half8*>(Pw + prow + ((kc * 64 + lgrp * 16) ^ pswz));
            int sb2 = (kc * 32 + lgrp * 8) * 2;
            #pragma unroll
            for (int nd = 0; nd < 4; ++nd) {
                int d  = nd * 16 + l16;
                int vo = d * 128 + (sb2 ^ ((d & 7) << 4));
                half8 vr = *(const half8*)(VR + vo);
                half8 vi = *(const half8*)(VI + vo);
                ore[nd] = __builtin_amdgcn_mfma_f32_16x16x32_f16(pa, vr, ore[nd], 0, 0, 0);
                oim[nd] = __builtin_amdgcn_mfma_f32_16x16x32_f16(pa, vi, oim[nd], 0, 0, 0);
            }
        }

        __syncthreads();                  // all reads of tile st complete
        if (st < 7) {
            stage_write();                // tile st+1 into the single buffers
            __syncthreads();              // LDS ready for tile st+1
        }
    }

    // ---------------- epilogue: O[l = lgrp*4+r][d = nd*16+l16] ----------------
    const size_t outImOff = (size_t)BB * NB * LL * HH * EE;
    #pragma unroll
    for (int r = 0; r < 4; ++r) {
        int lrow = l0 + lgrp * 4 + r;
        float ls  = __shfl(lsum, lgrp * 4 + r);
        float inv = 1.f / ls;
        size_t obase = ((size_t)bn * LL + lrow) * ROWSTRIDE + (size_t)h * EE;
        #pragma unroll
        for (int nd = 0; nd < 4; ++nd) {
            int d = nd * 16 + l16;
            out[obase + d]            = ore[nd][r] * inv;
            out[outImOff + obase + d] = oim[nd][r] * inv;
        }
    }
}

extern "C" void kernel_launch(void* const* d_in, const int* in_sizes, int n_in,
                              void* d_out, int out_size, void* d_ws, size_t ws_size,
                              hipStream_t stream) {
    const float* qre = (const float*)d_in[0];
    const float* qim = (const float*)d_in[1];
    const float* kre = (const float*)d_in[2];
    const float* kim = (const float*)d_in[3];
    const float* vre = (const float*)d_in[4];
    const float* vim = (const float*)d_in[5];
    float* out = (float*)d_out;
    dim3 grid(1024), block(512);
    hipLaunchKernelGGL(cattn_kernel, grid, block, 0, stream,
                       qre, qim, kre, kim, vre, vim, out);
}

// Round 13
// 87.224 us; speedup vs baseline: 3.0679x; 3.0679x over previous
//
#include <hip/hip_runtime.h>
#include <hip/hip_fp16.h>

typedef _Float16 half8 __attribute__((ext_vector_type(8)));
typedef _Float16 half4 __attribute__((ext_vector_type(4)));
typedef __fp16  fp16x2 __attribute__((ext_vector_type(2)));
typedef float f32x4 __attribute__((ext_vector_type(4)));

#define BB 4
#define NB 8
#define LL 512
#define SS 512
#define HH 8
#define EE 64
#define ROWSTRIDE (HH * EE)   // 512 floats between consecutive l (or s) rows

__device__ __forceinline__ unsigned pkh(float a, float b) {
    union { fp16x2 h; unsigned u; } c;
    c.h = __builtin_amdgcn_cvt_pkrtz(a, b);
    return c.u;
}

// R4 compute body, 16-WAVE blocks (1024 thr): each block = one head x 256
// Q-rows, so K/V staging is shared by 16 waves (was 8) -> K/V re-read traffic
// and per-wave staging work both halve. 512 blocks; LDS 96 KiB -> 1 block/CU
// = 16 waves/CU (same occupancy as R4's 2x8 -- co-residency deliberately NOT
// raised: R5/R11 showed >2 blocks/CU x 512thr thrashes L2/L3, FETCH x4-5).
// Schedule: load(t+1) -> QK(t) -> write(t+1 -> buf^1, overlapped) ->
// softmax+PV(t) -> barrier (1/tile). Per-wave structure identical to R4.

__global__ __launch_bounds__(1024, 4) void cattn_kernel(
    const float* __restrict__ qre, const float* __restrict__ qim,
    const float* __restrict__ kre, const float* __restrict__ kim,
    const float* __restrict__ vre, const float* __restrict__ vim,
    float* __restrict__ out)
{
    // 96 KiB total LDS -> 1 block/CU
    __shared__ __align__(16) _Float16 KtRe[2][64 * 64];  // [buf][s][e] swizzled
    __shared__ __align__(16) _Float16 KtIm[2][64 * 64];
    __shared__ __align__(16) _Float16 VtRe[2][64 * 64];  // [buf][d][s] swizzled
    __shared__ __align__(16) _Float16 VtIm[2][64 * 64];
    __shared__ __align__(16) _Float16 Pbuf[16][16 * 64]; // per-wave P[l][s] swizzled

    const int tid  = threadIdx.x;
    const int wave = tid >> 6;    // 0..15
    const int lane = tid & 63;
    const int lgrp = lane >> 4;   // 0..3
    const int l16  = lane & 15;   // 0..15

    // bijective XCD swizzle: nwg=512, 8 XCDs, 64 blocks per XCD chunk
    const int bid  = blockIdx.x;
    const int nid  = (bid & 7) * 64 + (bid >> 3);
    const int half = nid & 1;     // which 256-row half of L
    const int head = nid >> 1;    // 0..255
    const int h    = head & 7;
    const int bn   = head >> 3;

    const size_t headQ = (size_t)bn * LL * ROWSTRIDE + (size_t)h * EE;
    const size_t headK = (size_t)bn * SS * ROWSTRIDE + (size_t)h * EE;

    // staging registers (T14: load-early / write-late), 16 f32 total
    float4 ka, kb;       // K: one 8-elem e-chunk of one s-row, one array
    float2 vv[4];        // V: 4 s-rows x 2 d-cols

    // K: 2 arr x 64 s x 8 ec = 1024 items, 1/thread
    const int kEc0 = tid & 7;
    const int kS0  = (tid >> 3) & 63;
    const int kArr = tid >> 9;
    // V: 2 arr x 32 d-pairs x 16 s-groups = 1024 items, 1/thread
    const int vD0  = (tid & 31) * 2;
    const int vS0  = ((tid >> 5) & 15) * 4;
    const int vArr = tid >> 9;

    auto stage_load = [&](int st) {
        const int tb = st * 64;
        {
            const float* p = (kArr ? kim : kre) + headK + (size_t)(tb + kS0) * ROWSTRIDE + kEc0 * 8;
            ka = *(const float4*)p;
            kb = *(const float4*)(p + 4);
        }
        {
            const float* src = vArr ? vim : vre;
            #pragma unroll
            for (int i = 0; i < 4; ++i)
                vv[i] = *(const float2*)(src + headK + (size_t)(tb + vS0 + i) * ROWSTRIDE + vD0);
        }
    };

    auto stage_write = [&](int buf) {
        {
            union { half8 h; unsigned u[4]; } kv;
            kv.u[0] = pkh(ka.x, ka.y);
            kv.u[1] = pkh(ka.z, ka.w);
            kv.u[2] = pkh(kb.x, kb.y);
            kv.u[3] = pkh(kb.z, kb.w);
            _Float16* base = kArr ? KtIm[buf] : KtRe[buf];
            *reinterpret_cast<half8*>(reinterpret_cast<char*>(base) +
                kS0 * 128 + ((kEc0 * 16) ^ ((kS0 & 7) << 4))) = kv.h;
        }
        {
            _Float16* base = vArr ? VtIm[buf] : VtRe[buf];
            #pragma unroll
            for (int dd = 0; dd < 2; ++dd) {
                int d = vD0 + dd;
                union { half4 h; unsigned u[2]; } hv;
                hv.u[0] = pkh((&vv[0].x)[dd], (&vv[1].x)[dd]);
                hv.u[1] = pkh((&vv[2].x)[dd], (&vv[3].x)[dd]);
                *reinterpret_cast<half4*>(reinterpret_cast<char*>(base) +
                    d * 128 + ((vS0 * 2) ^ ((d & 7) << 4))) = hv.h;
            }
        }
    };

    // ---------------- Q fragments (B-operand: lane holds Q[l=l16][e=lgrp*8+j]) --
    const int l0 = half * 256 + wave * 16;
    half8 qr[2], qin[2];   // qr and -qi
    {
        size_t base = headQ + (size_t)(l0 + l16) * ROWSTRIDE + lgrp * 8;
        #pragma unroll
        for (int ec = 0; ec < 2; ++ec) {
            float4 a0 = *(const float4*)(qre + base + ec * 32);
            float4 a1 = *(const float4*)(qre + base + ec * 32 + 4);
            float4 b0 = *(const float4*)(qim + base + ec * 32);
            float4 b1 = *(const float4*)(qim + base + ec * 32 + 4);
            #pragma unroll
            for (int j = 0; j < 4; ++j) {
                qr[ec][j]      = (_Float16)((&a0.x)[j]);
                qr[ec][4 + j]  = (_Float16)((&a1.x)[j]);
                qin[ec][j]     = (_Float16)(-(&b0.x)[j]);
                qin[ec][4 + j] = (_Float16)(-(&b1.x)[j]);
            }
        }
    }

    f32x4 ore[4], oim[4];
    #pragma unroll
    for (int n = 0; n < 4; ++n) { ore[n] = (f32x4){0.f,0.f,0.f,0.f}; oim[n] = (f32x4){0.f,0.f,0.f,0.f}; }
    float m = -1e30f, lsum = 0.f;

    stage_load(0);
    stage_write(0);
    __syncthreads();

    char* Pw = reinterpret_cast<char*>(&Pbuf[wave][0]);
    const int prow = l16 * 128;
    const int pswz = (l16 & 7) << 4;

    // ---------------- main loop over 8 S-tiles ----------------
    for (int st = 0; st < 8; ++st) {
        const int cur = st & 1;
        if (st < 7) stage_load(st + 1);   // loads in flight during compute

        const char* KR = (const char*)KtRe[cur];
        const char* KI = (const char*)KtIm[cur];
        const char* VR = (const char*)VtRe[cur];
        const char* VI = (const char*)VtIm[cur];

        // scores^T: lane holds mag[s = n*16 + lgrp*4 + r][l = l16]
        float p_[4][4];
        float tmax = 0.f;
        #pragma unroll
        for (int n = 0; n < 4; ++n) {
            int srow = n * 16 + l16;
            int rb   = srow * 128;
            int swz  = (srow & 7) << 4;
            half8 kr0 = *(const half8*)(KR + rb + ((lgrp * 16)      ^ swz));
            half8 kr1 = *(const half8*)(KR + rb + ((64 + lgrp * 16) ^ swz));
            half8 ki0 = *(const half8*)(KI + rb + ((lgrp * 16)      ^ swz));
            half8 ki1 = *(const half8*)(KI + rb + ((64 + lgrp * 16) ^ swz));
            f32x4 z = (f32x4){0.f,0.f,0.f,0.f};
            z = __builtin_amdgcn_mfma_f32_16x16x32_f16(kr0, qr[0],  z, 0, 0, 0);
            z = __builtin_amdgcn_mfma_f32_16x16x32_f16(kr1, qr[1],  z, 0, 0, 0);
            z = __builtin_amdgcn_mfma_f32_16x16x32_f16(ki0, qin[0], z, 0, 0, 0);
            z = __builtin_amdgcn_mfma_f32_16x16x32_f16(ki1, qin[1], z, 0, 0, 0);
            f32x4 w = (f32x4){0.f,0.f,0.f,0.f};
            w = __builtin_amdgcn_mfma_f32_16x16x32_f16(ki0, qr[0],  w, 0, 0, 0);
            w = __builtin_amdgcn_mfma_f32_16x16x32_f16(ki1, qr[1],  w, 0, 0, 0);
            w = __builtin_amdgcn_mfma_f32_16x16x32_f16(kr0, qin[0], w, 0, 0, 0);
            w = __builtin_amdgcn_mfma_f32_16x16x32_f16(kr1, qin[1], w, 0, 0, 0);
            #pragma unroll
            for (int r = 0; r < 4; ++r) {
                float mg = __builtin_amdgcn_sqrtf(z[r] * z[r] + w[r] * w[r]);
                p_[n][r] = mg;
                tmax = fmaxf(tmax, mg);
            }
        }

        // early write: tile st+1 -> buf cur^1 (its last readers synced a
        // barrier ago); overlaps vmcnt-wait + ds_writes with softmax+PV
        if (st < 7) stage_write(cur ^ 1);

        // online softmax, one row per lane (4-way replicated across lgrps)
        tmax = fmaxf(tmax, __shfl_xor(tmax, 16));
        tmax = fmaxf(tmax, __shfl_xor(tmax, 32));
        float mn = fmaxf(m, tmax);
        // exact defer: if no row's max grew, sc == exp(0) == 1 -> skip rescale
        if (__any(tmax > m)) {
            float sc = __expf(m - mn);
            lsum *= sc;
            float scr[4];
            #pragma unroll
            for (int r = 0; r < 4; ++r) scr[r] = __shfl(sc, lgrp * 4 + r);
            #pragma unroll
            for (int n = 0; n < 4; ++n)
                #pragma unroll
                for (int r = 0; r < 4; ++r) { ore[n][r] *= scr[r]; oim[n][r] *= scr[r]; }
        }
        m = mn;
        float ps = 0.f;
        #pragma unroll
        for (int n = 0; n < 4; ++n)
            #pragma unroll
            for (int r = 0; r < 4; ++r) {
                float pe = __expf(p_[n][r] - mn);
                p_[n][r] = pe;
                ps += pe;
            }
        ps += __shfl_xor(ps, 16);
        ps += __shfl_xor(ps, 32);
        lsum += ps;

        // write P rows to per-wave LDS (wave-private)
        #pragma unroll
        for (int n = 0; n < 4; ++n) {
            uint2 val;
            val.x = pkh(p_[n][0], p_[n][1]);
            val.y = pkh(p_[n][2], p_[n][3]);
            *reinterpret_cast<uint2*>(Pw + prow + ((n * 32 + lgrp * 8) ^ pswz)) = val;
        }

        // PV: read A-frag P[l16][kc*32+lgrp*8 ..+7] from LDS, mfma against V^T
        #pragma unroll
        for (int kc = 0; kc < 2; ++kc) {
            half8 pa = *reinterpret_cast<const half8*>(Pw + prow + ((kc * 64 + lgrp * 16) ^ pswz));
            int sb2 = (kc * 32 + lgrp * 8) * 2;
            #pragma unroll
            for (int nd = 0; nd < 4; ++nd) {
                int d  = nd * 16 + l16;
                int vo = d * 128 + (sb2 ^ ((d & 7) << 4));
                half8 vr = *(const half8*)(VR + vo);
                half8 vi = *(const half8*)(VI + vo);
                ore[nd] = __builtin_amdgcn_mfma_f32_16x16x32_f16(pa, vr, ore[nd], 0, 0, 0);
                oim[nd] = __builtin_amdgcn_mfma_f32_16x16x32_f16(pa, vi, oim[nd], 0, 0, 0);
            }
        }

        __syncthreads();   // buf cur^1 writes complete; buf cur reads complete
    }

    // ---------------- epilogue: O[l = lgrp*4+r][d = nd*16+l16] ----------------
    const size_t outImOff = (size_t)BB * NB * LL * HH * EE;
    #pragma unroll
    for (int r = 0; r < 4; ++r) {
        int lrow = l0 + lgrp * 4 + r;
        float ls  = __shfl(lsum, lgrp * 4 + r);
        float inv = 1.f / ls;
        size_t obase = ((size_t)bn * LL + lrow) * ROWSTRIDE + (size_t)h * EE;
        #pragma unroll
        for (int nd = 0; nd < 4; ++nd) {
            int d = nd * 16 + l16;
            out[obase + d]            = ore[nd][r] * inv;
            out[outImOff + obase + d] = oim[nd][r] * inv;
        }
    }
}

extern "C" void kernel_launch(void* const* d_in, const int* in_sizes, int n_in,
                              void* d_out, int out_size, void* d_ws, size_t ws_size,
                              hipStream_t stream) {
    const float* qre = (const float*)d_in[0];
    const float* qim = (const float*)d_in[1];
    const float* kre = (const float*)d_in[2];
    const float* kim = (const float*)d_in[3];
    const float* vre = (const float*)d_in[4];
    const float* vim = (const float*)d_in[5];
    float* out = (float*)d_out;
    dim3 grid(512), block(1024);
    hipLaunchKernelGGL(cattn_kernel, grid, block, 0, stream,
                       qre, qim, kre, kim, vre, vim, out);
}